// Round 4
// baseline (132.244 us; speedup 1.0000x reference)
//
#include <hip/hip_runtime.h>

#define E_ 15000
#define D_ 200
#define L_ 64
#define B_ 256
#define BT 16
#define LOG2E 1.4426950408889634f

typedef float v2f __attribute__((ext_vector_type(2)));

// ws layout:
//   qt  @ 0      : D_*B_ f32    qt[d][b] = emb_e[e1[b],d]*emb_rel[rel[b],d]
//   swt @ 204800 : L_*B_ float2 swt[l][b] = { (lit[e1,l]-c[l])*r[l], nfw[rel,l] }
//   r   @ 335872 : L_ f32       r[l] = sqrt(log2e/var[l])
#define QT_OFF   0
#define SWT_OFF  204800
#define R_OFF    335872

__global__ __launch_bounds__(256) void setup_k(
    const float* __restrict__ emb_e, const float* __restrict__ emb_rel,
    const float* __restrict__ nfw,   const float* __restrict__ lit,
    const float* __restrict__ c,     const float* __restrict__ var,
    const int* __restrict__ e1,      const int* __restrict__ rel,
    float* __restrict__ qt, float2* __restrict__ swt, float* __restrict__ r)
{
    const int b = blockIdx.x;
    const int t = threadIdx.x;
    const int ie = e1[b];
    const int ir = rel[b];
    if (t < D_) qt[t * B_ + b] = emb_e[ie * D_ + t] * emb_rel[ir * D_ + t];
    if (t < L_) {
        const float rl = sqrtf(LOG2E / var[t]);
        swt[t * B_ + b] = make_float2((lit[ie * L_ + t] - c[t]) * rl,
                                      nfw[ir * L_ + t]);
        if (b == 0) r[t] = rl;
    }
}

// 512 threads: waves 0..3 (half=0) do d in [0,100), l in [0,32);
// waves 4..7 (half=1) do d in [100,200), l in [32,64) for the SAME e-range.
// Disjoint column halves -> per-block HBM traffic identical to the
// single-pass kernel, but 2x the waves/SIMD. Partials meet in LDS.
__global__ __launch_bounds__(512, 8) void main_k(
    const float* __restrict__ emb_e, const float* __restrict__ lit,
    const float* __restrict__ qt,    const float2* __restrict__ swt,
    const float* __restrict__ r,     float* __restrict__ out)
{
    __shared__ float qt_s[D_ * BT];   // 12.8 KB  [d][bb]
    __shared__ float su_s[L_ * BT];   //  4.0 KB  [l][bb]
    __shared__ float wt_s[L_ * BT];   //  4.0 KB  [l][bb]
    __shared__ float comb[BT * 256];  // 16.0 KB  [bb][elane] (conflict-free)

    const int tid  = threadIdx.x;
    const int half = tid >> 8;          // wave-uniform
    const int el   = tid & 255;
    const int e    = blockIdx.x * 256 + el;
    const int ec   = (e < E_) ? e : (E_ - 1);
    const int b0   = blockIdx.y * BT;

    // ---- stage per-b operands into LDS (read from L2, once per block) ----
    for (int i = tid; i < D_ * BT; i += 512)
        qt_s[i] = qt[(i >> 4) * B_ + b0 + (i & 15)];
    for (int i = tid; i < L_ * BT; i += 512) {
        const float2 v = swt[(i >> 4) * B_ + b0 + (i & 15)];
        su_s[i] = v.x;
        wt_s[i] = v.y;
    }
    __syncthreads();

    v2f acc[8];
    #pragma unroll
    for (int j = 0; j < 8; ++j) acc[j] = (v2f)(0.0f);

    const int dlo = half * 100;
    const int llo = half * 32;

    // ---- structural: acc += emb_e[ec, dlo..dlo+100) . qt_s rows ----
    const float* ee = emb_e + (size_t)ec * D_ + dlo;
    #pragma unroll 2
    for (int d = 0; d < 100; d += 4) {
        const float4 v4 = *(const float4*)(ee + d);
        const float va[4] = {v4.x, v4.y, v4.z, v4.w};
        #pragma unroll
        for (int k = 0; k < 4; ++k) {
            const v2f* qr = (const v2f*)&qt_s[(dlo + d + k) * BT];
            const v2f vs = {va[k], va[k]};
            #pragma unroll
            for (int j = 0; j < 8; ++j)
                acc[j] = __builtin_elementwise_fma(vs, qr[j], acc[j]);
        }
    }

    // ---- RBF: acc += exp2(-(su - x*r)^2) * wt over l-half ----
    const float* le = lit + (size_t)ec * L_ + llo;
    const float* rr = r + llo;
    #pragma unroll 1
    for (int l = 0; l < 32; l += 4) {
        const float4 x4 = *(const float4*)(le + l);
        const float4 r4 = *(const float4*)(rr + l);     // wave-uniform
        const float xa[4] = {x4.x, x4.y, x4.z, x4.w};
        const float ra[4] = {r4.x, r4.y, r4.z, r4.w};
        #pragma unroll
        for (int k = 0; k < 4; ++k) {
            const float u = xa[k] * ra[k];
            const v2f us = {u, u};
            const v2f* sr = (const v2f*)&su_s[(llo + l + k) * BT];
            const v2f* wr = (const v2f*)&wt_s[(llo + l + k) * BT];
            #pragma unroll
            for (int j = 0; j < 8; ++j) {
                const v2f t = sr[j] - us;
                const v2f m = -(t * t);
                const v2f ph = {__builtin_amdgcn_exp2f(m.x),
                                __builtin_amdgcn_exp2f(m.y)};
                acc[j] = __builtin_elementwise_fma(ph, wr[j], acc[j]);
            }
        }
    }

    // ---- combine halves in LDS, then sigmoid + coalesced store ----
    if (half) {
        #pragma unroll
        for (int j = 0; j < 8; ++j) {
            comb[(2 * j)     * 256 + el] = acc[j].x;
            comb[(2 * j + 1) * 256 + el] = acc[j].y;
        }
    }
    __syncthreads();
    if (!half && e < E_) {
        #pragma unroll
        for (int j = 0; j < 8; ++j) {
            #pragma unroll
            for (int h = 0; h < 2; ++h) {
                const int bb = 2 * j + h;
                const float z = (h ? acc[j].y : acc[j].x) + comb[bb * 256 + el];
                const float ezn = __builtin_amdgcn_exp2f(-z * LOG2E);
                out[(size_t)(b0 + bb) * E_ + e] =
                    __builtin_amdgcn_rcpf(1.0f + ezn);
            }
        }
    }
}

extern "C" void kernel_launch(void* const* d_in, const int* in_sizes, int n_in,
                              void* d_out, int out_size, void* d_ws, size_t ws_size,
                              hipStream_t stream) {
    const float* emb_e   = (const float*)d_in[0];
    const float* emb_rel = (const float*)d_in[1];
    const float* nfw     = (const float*)d_in[2];
    const float* lit     = (const float*)d_in[3];
    const float* c       = (const float*)d_in[4];
    const float* var     = (const float*)d_in[5];
    const int*   e1      = (const int*)d_in[6];
    const int*   rel     = (const int*)d_in[7];
    float* out = (float*)d_out;

    char* ws = (char*)d_ws;
    float*  qt  = (float*)(ws + QT_OFF);
    float2* swt = (float2*)(ws + SWT_OFF);
    float*  r   = (float*)(ws + R_OFF);

    setup_k<<<dim3(B_), dim3(256), 0, stream>>>(emb_e, emb_rel, nfw, lit, c, var,
                                                e1, rel, qt, swt, r);

    dim3 grid((E_ + 255) / 256, B_ / BT);
    main_k<<<grid, dim3(512), 0, stream>>>(emb_e, lit, qt, swt, r, out);
}

// Round 5
// 107.961 us; speedup vs baseline: 1.2249x; 1.2249x over previous
//
#include <hip/hip_runtime.h>

#define E_ 15000
#define D_ 200
#define L_ 64
#define B_ 256
#define LOG2E 1.4426950408889634f

typedef float v2f __attribute__((ext_vector_type(2)));

// ws layout:
//   qt @ 0      : D_*B_ f32  qt[d][b] = emb_e[e1[b],d]*emb_rel[rel[b],d]
//   su @ 204800 : L_*B_ f32  su[l][b] = (lit[e1,l]-c[l])*r[l]
//   wt @ 270336 : L_*B_ f32  wt[l][b] = nfw[rel,l]
//   r  @ 335872 : L_ f32     r[l] = sqrt(log2e/var[l])
#define QT_OFF 0
#define SU_OFF 204800
#define WT_OFF 270336
#define R_OFF  335872

__global__ __launch_bounds__(256) void setup_k(
    const float* __restrict__ emb_e, const float* __restrict__ emb_rel,
    const float* __restrict__ nfw,   const float* __restrict__ lit,
    const float* __restrict__ c,     const float* __restrict__ var,
    const int* __restrict__ e1,      const int* __restrict__ rel,
    float* __restrict__ qt, float* __restrict__ su,
    float* __restrict__ wt, float* __restrict__ r)
{
    const int b = blockIdx.x;
    const int t = threadIdx.x;
    const int ie = e1[b];
    const int ir = rel[b];
    if (t < D_) qt[t * B_ + b] = emb_e[ie * D_ + t] * emb_rel[ir * D_ + t];
    if (t < L_) {
        const float rl = sqrtf(LOG2E / var[t]);
        su[t * B_ + b] = (lit[ie * L_ + t] - c[t]) * rl;
        wt[t * B_ + b] = nfw[ir * L_ + t];
        if (b == 0) r[t] = rl;
    }
}

// 940 blocks (235 e-tiles x 4 b-groups), 256 threads = 4 waves.
// Wave s owns the reduction slice d in [50s,50s+50), l in [16s,16s+16).
// Each thread keeps its e-row slice (50 emb_e + 16 lit-derived) in REGISTERS,
// loaded once, reused for all 64 b's. Per-b operands (qt/su/wt/r) are
// wave-uniform -> s_load broadcasts. Partials combine via LDS per 16-b chunk.
__global__ __launch_bounds__(256, 4) void main_k(
    const float* __restrict__ emb_e, const float* __restrict__ lit,
    const float* __restrict__ qt,    const float* __restrict__ su,
    const float* __restrict__ wt,    const float* __restrict__ r,
    float* __restrict__ out)
{
    __shared__ float comb[4][16][64];   // 16 KB [split][bb][lane]

    // Bijective XCD swizzle (nwg=940, q=117, rem=4): XCD k gets a contiguous
    // orig range; orig enumerates b-groups fastest -> each XCD sees ~29
    // e-tiles (2 MB of emb_e/lit), L2-resident across its 4 b-sweeps.
    const int w    = blockIdx.x;
    const int xcd  = w & 7;
    const int slot = w >> 3;
    const int orig = (xcd < 4) ? (xcd * 118 + slot)
                               : (4 * 118 + (xcd - 4) * 117 + slot);
    const int x = orig >> 2;        // e-tile 0..234
    const int y = orig & 3;         // b-group 0..3

    const int lane = threadIdx.x & 63;
    const int s    = __builtin_amdgcn_readfirstlane(threadIdx.x >> 6); // split
    const int e    = x * 64 + lane;
    const int ec   = (e < E_) ? e : (E_ - 1);
    const int d0   = s * 50;
    const int l0   = s * 16;

    // ---- one-time register-resident loads ----
    float ee[50];
    {
        const float* ep = emb_e + (size_t)ec * D_ + d0;   // 8B aligned
        #pragma unroll
        for (int i = 0; i < 25; ++i) {
            const v2f v = *(const v2f*)(ep + 2 * i);
            ee[2 * i] = v.x; ee[2 * i + 1] = v.y;
        }
    }
    float u[16];                                          // u[l] = lit*r (chunk-invariant)
    {
        const float* lp = lit + (size_t)ec * L_ + l0;     // 16B aligned
        #pragma unroll
        for (int i = 0; i < 4; ++i) {
            const float4 v = *(const float4*)(lp + 4 * i);
            u[4*i]   = v.x * r[l0 + 4*i];
            u[4*i+1] = v.y * r[l0 + 4*i + 1];
            u[4*i+2] = v.z * r[l0 + 4*i + 2];
            u[4*i+3] = v.w * r[l0 + 4*i + 3];
        }
    }

    // ---- 4 chunks of 16 b's ----
    #pragma unroll 1
    for (int ch = 0; ch < 4; ++ch) {
        const int b0 = y * 64 + ch * 16;

        v2f acc[8];
        #pragma unroll
        for (int j = 0; j < 8; ++j) acc[j] = (v2f)(0.0f);

        // structural: acc[bb] += ee[d] * qt[d0+d][b0+bb]   (qt via s_load)
        #pragma unroll
        for (int d = 0; d < 50; ++d) {
            const v2f* q2 = (const v2f*)(qt + (d0 + d) * B_ + b0);
            const v2f ev = {ee[d], ee[d]};
            #pragma unroll
            for (int j = 0; j < 8; ++j)
                acc[j] = __builtin_elementwise_fma(ev, q2[j], acc[j]);
        }

        // RBF: acc[bb] += exp2(-(su-u)^2) * wt
        #pragma unroll
        for (int l = 0; l < 16; ++l) {
            const v2f* s2 = (const v2f*)(su + (l0 + l) * B_ + b0);
            const v2f* w2 = (const v2f*)(wt + (l0 + l) * B_ + b0);
            const v2f uv = {u[l], u[l]};
            #pragma unroll
            for (int j = 0; j < 8; ++j) {
                const v2f t = s2[j] - uv;
                const v2f m = -(t * t);
                const v2f ph = {__builtin_amdgcn_exp2f(m.x),
                                __builtin_amdgcn_exp2f(m.y)};
                acc[j] = __builtin_elementwise_fma(ph, w2[j], acc[j]);
            }
        }

        // combine 4 splits in LDS; wave s finalizes bb in [4s,4s+4)
        #pragma unroll
        for (int j = 0; j < 8; ++j) {
            comb[s][2 * j][lane]     = acc[j].x;
            comb[s][2 * j + 1][lane] = acc[j].y;
        }
        __syncthreads();
        if (e < E_) {
            #pragma unroll
            for (int bi = 0; bi < 4; ++bi) {
                const int bb = 4 * s + bi;
                const float z = comb[0][bb][lane] + comb[1][bb][lane]
                              + comb[2][bb][lane] + comb[3][bb][lane];
                const float ezn = __builtin_amdgcn_exp2f(-z * LOG2E);
                out[(size_t)(b0 + bb) * E_ + e] =
                    __builtin_amdgcn_rcpf(1.0f + ezn);
            }
        }
        __syncthreads();
    }
}

extern "C" void kernel_launch(void* const* d_in, const int* in_sizes, int n_in,
                              void* d_out, int out_size, void* d_ws, size_t ws_size,
                              hipStream_t stream) {
    const float* emb_e   = (const float*)d_in[0];
    const float* emb_rel = (const float*)d_in[1];
    const float* nfw     = (const float*)d_in[2];
    const float* lit     = (const float*)d_in[3];
    const float* c       = (const float*)d_in[4];
    const float* var     = (const float*)d_in[5];
    const int*   e1      = (const int*)d_in[6];
    const int*   rel     = (const int*)d_in[7];
    float* out = (float*)d_out;

    char* ws = (char*)d_ws;
    float* qt = (float*)(ws + QT_OFF);
    float* su = (float*)(ws + SU_OFF);
    float* wt = (float*)(ws + WT_OFF);
    float* r  = (float*)(ws + R_OFF);

    setup_k<<<dim3(B_), dim3(256), 0, stream>>>(emb_e, emb_rel, nfw, lit, c, var,
                                                e1, rel, qt, su, wt, r);

    main_k<<<dim3(940), dim3(256), 0, stream>>>(emb_e, lit, qt, su, wt, r, out);
}